// Round 2
// baseline (85.716 us; speedup 1.0000x reference)
//
#include <hip/hip_runtime.h>

constexpr int BATCH = 256;
constexpr int CH    = 512;
constexpr int KS    = 5;
constexpr int PAD   = (KS - 1) / 2;  // 'same' padding = 2

#define LOG2E 1.4426950408889634f

// ---------------- Kernel A: conv1d (cross-correlation, zero-pad) ----------------
// One block per batch. Writes qh (pre-scaled by log2e), kh, vh to global scratch,
// plus per-batch max/min of kh for the stable-softmax row max.
__global__ __launch_bounds__(CH, 2) void conv_kernel(
    const float* __restrict__ q, const float* __restrict__ k, const float* __restrict__ v,
    const float* __restrict__ wq, const float* __restrict__ wk, const float* __restrict__ wv,
    float* __restrict__ qh, float* __restrict__ kh, float* __restrict__ vh,
    float* __restrict__ kmax, float* __restrict__ kmin)
{
    __shared__ float sq[CH], sk[CH], sv[CH];
    __shared__ float wred_max[8], wred_min[8];

    const int b = blockIdx.x;
    const int t = threadIdx.x;

    sq[t] = q[b * CH + t];
    sk[t] = k[b * CH + t];
    sv[t] = v[b * CH + t];

    float w_q[KS], w_k[KS], w_v[KS];
#pragma unroll
    for (int j = 0; j < KS; ++j) { w_q[j] = wq[j]; w_k[j] = wk[j]; w_v[j] = wv[j]; }
    __syncthreads();

    float aq = 0.f, ak = 0.f, av = 0.f;
#pragma unroll
    for (int j = 0; j < KS; ++j) {
        const int idx = t + j - PAD;
        if (idx >= 0 && idx < CH) {
            aq = fmaf(sq[idx], w_q[j], aq);
            ak = fmaf(sk[idx], w_k[j], ak);
            av = fmaf(sv[idx], w_v[j], av);
        }
    }
    qh[b * CH + t] = aq * LOG2E;  // pre-scale into exp2 domain
    kh[b * CH + t] = ak;
    vh[b * CH + t] = av;

    // block max/min of kh
    float lmax = ak, lmin = ak;
#pragma unroll
    for (int off = 32; off > 0; off >>= 1) {
        lmax = fmaxf(lmax, __shfl_down(lmax, off, 64));
        lmin = fminf(lmin, __shfl_down(lmin, off, 64));
    }
    const int wave = t >> 6;
    if ((t & 63) == 0) { wred_max[wave] = lmax; wred_min[wave] = lmin; }
    __syncthreads();
    if (t == 0) {
        float m = wred_max[0], n = wred_min[0];
#pragma unroll
        for (int i = 1; i < 8; ++i) { m = fmaxf(m, wred_max[i]); n = fminf(n, wred_min[i]); }
        kmax[b] = m;
        kmin[b] = n;
    }
}

// ---------------- Kernel B: rank-1 softmax-attention ----------------
// scores[c,d] = qh[c]*kh[d]; softmax over d; dot with vh.
// kh/vh/kmax/kmin are read with wave-uniform addresses -> scalar (SMEM) loads;
// the inner loop is then pure v_fma + v_exp on the VALU/trans pipes.
__global__ __launch_bounds__(CH, 2) void attn_kernel(
    const float* __restrict__ qh, const float* __restrict__ kh, const float* __restrict__ vh,
    const float* __restrict__ kmax, const float* __restrict__ kmin,
    float* __restrict__ out)
{
    const int b = blockIdx.x;
    const int t = threadIdx.x;

    const float qc = qh[b * CH + t];            // already × log2e
    const float kmx = kmax[b];                  // uniform -> s_load
    const float kmn = kmin[b];
    const float m2 = fmaxf(qc * kmx, qc * kmn); // row max in exp2 domain

    const float4* __restrict__ kh4 = (const float4*)(kh + b * CH);
    const float4* __restrict__ vh4 = (const float4*)(vh + b * CH);

    float den = 0.f, num = 0.f;
#pragma unroll 8
    for (int d4 = 0; d4 < CH / 4; ++d4) {
        const float4 kk = kh4[d4];              // uniform -> s_load_dwordx4
        const float4 vv = vh4[d4];
        const float e0 = exp2f(fmaf(qc, kk.x, -m2));
        const float e1 = exp2f(fmaf(qc, kk.y, -m2));
        const float e2 = exp2f(fmaf(qc, kk.z, -m2));
        const float e3 = exp2f(fmaf(qc, kk.w, -m2));
        den += (e0 + e1) + (e2 + e3);
        num = fmaf(e0, vv.x, num);
        num = fmaf(e1, vv.y, num);
        num = fmaf(e2, vv.z, num);
        num = fmaf(e3, vv.w, num);
    }

    out[b * CH + t] = num / den;
}

extern "C" void kernel_launch(void* const* d_in, const int* in_sizes, int n_in,
                              void* d_out, int out_size, void* d_ws, size_t ws_size,
                              hipStream_t stream) {
    const float* q  = (const float*)d_in[0];
    const float* k  = (const float*)d_in[1];
    const float* v  = (const float*)d_in[2];
    const float* wq = (const float*)d_in[3];
    const float* wk = (const float*)d_in[4];
    const float* wv = (const float*)d_in[5];
    float* out = (float*)d_out;

    float* ws   = (float*)d_ws;
    float* qh   = ws;                     // 256*512
    float* kh   = ws + BATCH * CH;        // 256*512
    float* vh   = ws + 2 * BATCH * CH;    // 256*512
    float* kmax = ws + 3 * BATCH * CH;    // 256
    float* kmin = kmax + BATCH;           // 256

    conv_kernel<<<BATCH, CH, 0, stream>>>(q, k, v, wq, wk, wv, qh, kh, vh, kmax, kmin);
    attn_kernel<<<BATCH, CH, 0, stream>>>(qh, kh, vh, kmax, kmin, out);
}

// Round 3
// 83.586 us; speedup vs baseline: 1.0255x; 1.0255x over previous
//
#include <hip/hip_runtime.h>

constexpr int BATCH = 256;
constexpr int CH    = 512;
constexpr int KS    = 5;
constexpr int PAD   = (KS - 1) / 2;  // 'same' padding = 2
constexpr int NT    = 256;           // threads/block: 4 waves, 2 rows per thread

#define LOG2E 1.4426950408889634f

// Single fused kernel: one block per batch, 256 threads, each thread owns
// rows t and t+256. Rank-1 attention: scores[c,d] = qh[c]*kh[d], softmax
// over d, dot with vh. kh/vh broadcast-read from LDS once per float4 and
// reused for BOTH rows -> halves the per-CU LDS instruction count vs 1
// row/thread (LDS unit is per-CU shared; it was the R1 bottleneck).
__global__ __launch_bounds__(NT, 2) void attn1d_kernel(
    const float* __restrict__ q, const float* __restrict__ k, const float* __restrict__ v,
    const float* __restrict__ wq, const float* __restrict__ wk, const float* __restrict__ wv,
    float* __restrict__ out)
{
    __shared__ float sq[CH], sk[CH], sv[CH];   // raw input rows
    __shared__ float kh[CH], vh[CH];           // conv outputs (broadcast source)
    __shared__ float wred_max[4], wred_min[4];
    __shared__ float s_kmax, s_kmin;

    const int b = blockIdx.x;
    const int t = threadIdx.x;

    // Stage input rows: 2 coalesced float2 loads per array per thread.
    {
        const float2* q2 = (const float2*)(q + b * CH);
        const float2* k2 = (const float2*)(k + b * CH);
        const float2* v2 = (const float2*)(v + b * CH);
        ((float2*)sq)[t] = q2[t];
        ((float2*)sk)[t] = k2[t];
        ((float2*)sv)[t] = v2[t];
    }

    float w_q[KS], w_k[KS], w_v[KS];
#pragma unroll
    for (int j = 0; j < KS; ++j) { w_q[j] = wq[j]; w_k[j] = wk[j]; w_v[j] = wv[j]; }
    __syncthreads();

    // Conv (cross-correlation, zero-pad) for rows r0 = t and r1 = t + 256.
    const int r0 = t, r1 = t + NT;
    float aq0 = 0.f, ak0 = 0.f, av0 = 0.f;
    float aq1 = 0.f, ak1 = 0.f, av1 = 0.f;
#pragma unroll
    for (int j = 0; j < KS; ++j) {
        const int i0 = r0 + j - PAD;
        const int i1 = r1 + j - PAD;
        if (i0 >= 0 && i0 < CH) {
            aq0 = fmaf(sq[i0], w_q[j], aq0);
            ak0 = fmaf(sk[i0], w_k[j], ak0);
            av0 = fmaf(sv[i0], w_v[j], av0);
        }
        if (i1 >= 0 && i1 < CH) {
            aq1 = fmaf(sq[i1], w_q[j], aq1);
            ak1 = fmaf(sk[i1], w_k[j], ak1);
            av1 = fmaf(sv[i1], w_v[j], av1);
        }
    }
    kh[r0] = ak0; vh[r0] = av0;
    kh[r1] = ak1; vh[r1] = av1;

    // Block max/min of kh (each thread contributes both its rows).
    float lmax = fmaxf(ak0, ak1), lmin = fminf(ak0, ak1);
#pragma unroll
    for (int off = 32; off > 0; off >>= 1) {
        lmax = fmaxf(lmax, __shfl_down(lmax, off, 64));
        lmin = fminf(lmin, __shfl_down(lmin, off, 64));
    }
    const int wave = t >> 6;
    if ((t & 63) == 0) { wred_max[wave] = lmax; wred_min[wave] = lmin; }
    __syncthreads();  // also publishes kh/vh
    if (t == 0) {
        float m = wred_max[0], n = wred_min[0];
#pragma unroll
        for (int i = 1; i < 4; ++i) { m = fmaxf(m, wred_max[i]); n = fminf(n, wred_min[i]); }
        s_kmax = m; s_kmin = n;
    }
    __syncthreads();

    // Pre-scale into exp2 domain; per-row exact max for stable softmax.
    const float qc0 = aq0 * LOG2E, qc1 = aq1 * LOG2E;
    const float kmx = s_kmax * LOG2E, kmn = s_kmin * LOG2E;
    // row max of qc*kh over d (in exp2 domain): sign-select via max of both
    const float m0 = fmaxf(aq0 * kmx, aq0 * kmn);
    const float m1 = fmaxf(aq1 * kmx, aq1 * kmn);

    float den0 = 0.f, num0 = 0.f, den1 = 0.f, num1 = 0.f;
    const float4* kh4 = (const float4*)kh;
    const float4* vh4 = (const float4*)vh;
#pragma unroll 4
    for (int d4 = 0; d4 < CH / 4; ++d4) {
        const float4 kk = kh4[d4];   // same addr across wave -> LDS broadcast
        const float4 vv = vh4[d4];
        // row 0
        const float a0 = exp2f(fmaf(qc0, kk.x, -m0));
        const float a1 = exp2f(fmaf(qc0, kk.y, -m0));
        const float a2 = exp2f(fmaf(qc0, kk.z, -m0));
        const float a3 = exp2f(fmaf(qc0, kk.w, -m0));
        den0 += (a0 + a1) + (a2 + a3);
        num0 = fmaf(a0, vv.x, num0);
        num0 = fmaf(a1, vv.y, num0);
        num0 = fmaf(a2, vv.z, num0);
        num0 = fmaf(a3, vv.w, num0);
        // row 1 (reuses kk/vv -> no extra LDS traffic)
        const float b0 = exp2f(fmaf(qc1, kk.x, -m1));
        const float b1 = exp2f(fmaf(qc1, kk.y, -m1));
        const float b2 = exp2f(fmaf(qc1, kk.z, -m1));
        const float b3 = exp2f(fmaf(qc1, kk.w, -m1));
        den1 += (b0 + b1) + (b2 + b3);
        num1 = fmaf(b0, vv.x, num1);
        num1 = fmaf(b1, vv.y, num1);
        num1 = fmaf(b2, vv.z, num1);
        num1 = fmaf(b3, vv.w, num1);
    }

    out[b * CH + r0] = num0 / den0;
    out[b * CH + r1] = num1 / den1;
}

extern "C" void kernel_launch(void* const* d_in, const int* in_sizes, int n_in,
                              void* d_out, int out_size, void* d_ws, size_t ws_size,
                              hipStream_t stream) {
    const float* q  = (const float*)d_in[0];
    const float* k  = (const float*)d_in[1];
    const float* v  = (const float*)d_in[2];
    const float* wq = (const float*)d_in[3];
    const float* wk = (const float*)d_in[4];
    const float* wv = (const float*)d_in[5];
    float* out = (float*)d_out;

    attn1d_kernel<<<BATCH, NT, 0, stream>>>(q, k, v, wq, wk, wv, out);
}

// Round 4
// 79.492 us; speedup vs baseline: 1.0783x; 1.0515x over previous
//
#include <hip/hip_runtime.h>

constexpr int BATCH = 256;
constexpr int CH    = 512;
constexpr int KS    = 5;
constexpr int PAD   = (KS - 1) / 2;  // 'same' padding = 2

#define LOG2E 1.4426950408889634f

// One block per batch, one thread per row. Rank-1 attention:
// scores[c,d] = qh[c]*kh[d], softmax over d, dot with vh.
// 512 threads = 8 waves = 2 waves/SIMD -> VALU and trans (v_exp) pipes
// overlap across waves (R3's 1 wave/SIMD serialized them: 83.6 vs 75.5 us).
// Inner loop works in exp2 domain: 1 v_fma + 1 v_exp per score term.
__global__ __launch_bounds__(CH, 2) void attn1d_kernel(
    const float* __restrict__ q, const float* __restrict__ k, const float* __restrict__ v,
    const float* __restrict__ wq, const float* __restrict__ wk, const float* __restrict__ wv,
    float* __restrict__ out)
{
    __shared__ float sq[CH], sk[CH], sv[CH];   // raw input rows
    __shared__ float kh[CH], vh[CH];           // conv outputs (broadcast source)
    __shared__ float wred_max[8], wred_min[8];
    __shared__ float s_kmax, s_kmin;

    const int b = blockIdx.x;
    const int t = threadIdx.x;

    // Stage input rows (coalesced dword loads, 2 KB per array).
    sq[t] = q[b * CH + t];
    sk[t] = k[b * CH + t];
    sv[t] = v[b * CH + t];

    float w_q[KS], w_k[KS], w_v[KS];
#pragma unroll
    for (int j = 0; j < KS; ++j) { w_q[j] = wq[j]; w_k[j] = wk[j]; w_v[j] = wv[j]; }
    __syncthreads();

    // 'same' cross-correlation (XLA conv does not flip), zero-padded.
    float aq = 0.f, ak = 0.f, av = 0.f;
#pragma unroll
    for (int j = 0; j < KS; ++j) {
        const int idx = t + j - PAD;
        if (idx >= 0 && idx < CH) {
            aq = fmaf(sq[idx], w_q[j], aq);
            ak = fmaf(sk[idx], w_k[j], ak);
            av = fmaf(sv[idx], w_v[j], av);
        }
    }
    kh[t] = ak;
    vh[t] = av;

    // Block max/min of kh -> exact per-row score max for stable softmax.
    float lmax = ak, lmin = ak;
#pragma unroll
    for (int off = 32; off > 0; off >>= 1) {
        lmax = fmaxf(lmax, __shfl_down(lmax, off, 64));
        lmin = fminf(lmin, __shfl_down(lmin, off, 64));
    }
    const int wave = t >> 6;
    if ((t & 63) == 0) { wred_max[wave] = lmax; wred_min[wave] = lmin; }
    __syncthreads();  // also publishes kh/vh
    if (t == 0) {
        float m = wred_max[0], n = wred_min[0];
#pragma unroll
        for (int i = 1; i < 8; ++i) { m = fmaxf(m, wred_max[i]); n = fminf(n, wred_min[i]); }
        s_kmax = m; s_kmin = n;
    }
    __syncthreads();

    // exp2 domain: qc pre-scaled by log2e; row max via sign-select.
    const float qc = aq * LOG2E;
    const float m2 = fmaxf(qc * s_kmax, qc * s_kmin);

    // 128 iters x (2 broadcast ds_read_b128 + 4 exp2 + 11 VALU).
    float den = 0.f, num = 0.f;
    const float4* kh4 = (const float4*)kh;
    const float4* vh4 = (const float4*)vh;
#pragma unroll 4
    for (int d4 = 0; d4 < CH / 4; ++d4) {
        const float4 kk = kh4[d4];   // same addr across wave -> LDS broadcast
        const float4 vv = vh4[d4];
        const float e0 = exp2f(fmaf(qc, kk.x, -m2));
        const float e1 = exp2f(fmaf(qc, kk.y, -m2));
        const float e2 = exp2f(fmaf(qc, kk.z, -m2));
        const float e3 = exp2f(fmaf(qc, kk.w, -m2));
        den += (e0 + e1) + (e2 + e3);
        num = fmaf(e0, vv.x, num);
        num = fmaf(e1, vv.y, num);
        num = fmaf(e2, vv.z, num);
        num = fmaf(e3, vv.w, num);
    }

    out[b * CH + t] = num / den;
}

extern "C" void kernel_launch(void* const* d_in, const int* in_sizes, int n_in,
                              void* d_out, int out_size, void* d_ws, size_t ws_size,
                              hipStream_t stream) {
    const float* q  = (const float*)d_in[0];
    const float* k  = (const float*)d_in[1];
    const float* v  = (const float*)d_in[2];
    const float* wq = (const float*)d_in[3];
    const float* wk = (const float*)d_in[4];
    const float* wv = (const float*)d_in[5];
    float* out = (float*)d_out;

    attn1d_kernel<<<BATCH, CH, 0, stream>>>(q, k, v, wq, wk, wv, out);
}